// Round 1
// baseline (6316.106 us; speedup 1.0000x reference)
//
#include <hip/hip_runtime.h>
#include <hip/hip_bf16.h>

// Problem constants
#define BB 16
#define NN 1024
#define CC 768
#define HH 12
#define DH 64
#define NSC 196
#define N1 1220              // NN + NSC
#define M_QKV (BB * N1)      // 19520
#define N_QKV (3 * CC)       // 2304
#define M_PROJ (BB * NN)     // 16384

// ---------------------------------------------------------------------------
// Kernel 1: QKV GEMM.  C[m][n] = xt[m][:] . W_qkv[:][n], xt = concat(x, sc).
// M=19520, K=768, N=2304. 64x64 tile, BK=16, 256 threads, 4x4 per thread.
// Output stored as bf16 (error budget analysis: final absmax ~2e-4 << 2.05e-3).
// ---------------------------------------------------------------------------
__global__ __launch_bounds__(256) void qkv_gemm_kernel(
    const float* __restrict__ x, const float* __restrict__ sct,
    const float* __restrict__ W, __hip_bfloat16* __restrict__ out)
{
    __shared__ float As[16][68];   // [k][m], padded to 17 float4 (272B rows)
    __shared__ float Bs[16][64];   // [k][n]

    const int t  = threadIdx.x;
    const int n0 = blockIdx.x * 64;
    const int m0 = blockIdx.y * 64;

    // A-tile load mapping: thread t loads row m0 + t/4, cols (t%4)*4 .. +3
    const int ar = t >> 2;
    const int ac = (t & 3) * 4;
    const int r  = m0 + ar;
    const int bidx = r / N1;
    const int rr   = r - bidx * N1;
    const float* arow = (rr < NN)
        ? (x   + ((size_t)bidx * NN + rr) * CC)
        : (sct + (size_t)(rr - NN) * CC);

    // B-tile load mapping: thread t loads row t/16, cols (t%16)*4 .. +3
    const int br = t >> 4;
    const int bc = (t & 15) * 4;
    const float* bptr = W + (size_t)br * N_QKV + n0 + bc;

    const int tm = (t & 15) * 4;   // output micro-tile row offset
    const int tn = (t >> 4) * 4;   // output micro-tile col offset

    float acc[4][4] = {};

    for (int k0 = 0; k0 < CC; k0 += 16) {
        float4 av = *(const float4*)(arow + k0 + ac);
        float4 bv = *(const float4*)(bptr + (size_t)k0 * N_QKV);
        __syncthreads();
        As[ac + 0][ar] = av.x;
        As[ac + 1][ar] = av.y;
        As[ac + 2][ar] = av.z;
        As[ac + 3][ar] = av.w;
        *(float4*)(&Bs[br][bc]) = bv;
        __syncthreads();
#pragma unroll
        for (int kk = 0; kk < 16; ++kk) {
            float4 a4 = *(const float4*)(&As[kk][tm]);
            float4 b4 = *(const float4*)(&Bs[kk][tn]);
            float a[4] = {a4.x, a4.y, a4.z, a4.w};
            float b[4] = {b4.x, b4.y, b4.z, b4.w};
#pragma unroll
            for (int u = 0; u < 4; ++u)
#pragma unroll
                for (int v = 0; v < 4; ++v)
                    acc[u][v] = fmaf(a[u], b[v], acc[u][v]);
        }
    }

    const size_t obase = (size_t)(m0 + tm) * N_QKV + n0 + tn;
#pragma unroll
    for (int u = 0; u < 4; ++u)
#pragma unroll
        for (int v = 0; v < 4; ++v)
            out[obase + (size_t)u * N_QKV + v] = __float2bfloat16(acc[u][v]);
}

// ---------------------------------------------------------------------------
// Kernel 2: attention. One block per (b, h, 8-query tile). Only the first
// 1024 queries per batch are computed (output is sliced to [:, :N, :]).
// Scores for the whole 1220-key row kept in LDS; two-pass softmax.
// qkv layout: row = b*N1 + token, col = which*768 + h*64 + d.
// ---------------------------------------------------------------------------
__global__ __launch_bounds__(256) void attn_kernel(
    const __hip_bfloat16* __restrict__ qkv, float* __restrict__ attn_out)
{
    __shared__ float sc[8][N1];      // 39040 B
    __shared__ float qs[8][64];      //  2048 B
    __shared__ float kv[64][68];     // 17408 B (padded)

    const int t   = threadIdx.x;
    const int bid = blockIdx.x;
    const int qt  = bid & 127;              // query tile 0..127
    const int h   = (bid >> 7) % HH;
    const int b   = bid / (128 * HH);

    const size_t rowbase = (size_t)b * N1;
    const int qcol = h * DH;                // q col base
    const int kcol = CC + h * DH;           // k col base
    const int vcol = 2 * CC + h * DH;       // v col base

    // load 8 q rows
    for (int idx = t; idx < 8 * 64; idx += 256) {
        int i = idx >> 6, d = idx & 63;
        qs[i][d] = __bfloat162float(
            qkv[(rowbase + qt * 8 + i) * N_QKV + qcol + d]);
    }

    const int jl = t & 63;     // key index within tile
    const int ib = t >> 6;     // wave id 0..3; handles rows ib and ib+4

    // ---- scores ----
    for (int j0 = 0; j0 < N1; j0 += 64) {
        const int jn = min(64, N1 - j0);
        __syncthreads();
        for (int idx = t; idx < jn * 64; idx += 256) {
            int j = idx >> 6, d = idx & 63;
            kv[j][d] = __bfloat162float(
                qkv[(rowbase + j0 + j) * N_QKV + kcol + d]);
        }
        __syncthreads();
        if (jl < jn) {
            float s0 = 0.f, s1 = 0.f;
#pragma unroll
            for (int d4 = 0; d4 < 16; ++d4) {
                float4 k4 = *(const float4*)(&kv[jl][d4 * 4]);
                float4 qa = *(const float4*)(&qs[ib][d4 * 4]);
                float4 qb = *(const float4*)(&qs[ib + 4][d4 * 4]);
                s0 += k4.x * qa.x + k4.y * qa.y + k4.z * qa.z + k4.w * qa.w;
                s1 += k4.x * qb.x + k4.y * qb.y + k4.z * qb.z + k4.w * qb.w;
            }
            sc[ib][j0 + jl]     = s0 * 0.125f;
            sc[ib + 4][j0 + jl] = s1 * 0.125f;
        }
    }
    __syncthreads();

    // ---- softmax, one wave per 2 rows ----
    const int lane = t & 63;
#pragma unroll
    for (int p = 0; p < 2; ++p) {
        const int i = ib + p * 4;
        float m = -1e30f;
        for (int j = lane; j < N1; j += 64) m = fmaxf(m, sc[i][j]);
#pragma unroll
        for (int off = 32; off; off >>= 1) m = fmaxf(m, __shfl_down(m, off));
        m = __shfl(m, 0);
        float sum = 0.f;
        for (int j = lane; j < N1; j += 64) {
            float e = __expf(sc[i][j] - m);
            sc[i][j] = e;
            sum += e;
        }
#pragma unroll
        for (int off = 32; off; off >>= 1) sum += __shfl_down(sum, off);
        sum = __shfl(sum, 0);
        const float inv = 1.0f / sum;
        for (int j = lane; j < N1; j += 64) sc[i][j] *= inv;
    }

    // ---- PV ----
    float acc0 = 0.f, acc1 = 0.f;
    const int d = t & 63;
    for (int j0 = 0; j0 < N1; j0 += 64) {
        const int jn = min(64, N1 - j0);
        __syncthreads();
        for (int idx = t; idx < jn * 64; idx += 256) {
            int j = idx >> 6, dd = idx & 63;
            kv[j][dd] = __bfloat162float(
                qkv[(rowbase + j0 + j) * N_QKV + vcol + dd]);
        }
        __syncthreads();
        for (int j = 0; j < jn; ++j) {
            float vv = kv[j][d];
            acc0 = fmaf(sc[ib][j0 + j], vv, acc0);
            acc1 = fmaf(sc[ib + 4][j0 + j], vv, acc1);
        }
    }

    const size_t orow0 = (size_t)(b * NN + qt * 8 + ib) * CC + h * DH + d;
    const size_t orow1 = (size_t)(b * NN + qt * 8 + ib + 4) * CC + h * DH + d;
    attn_out[orow0] = acc0;
    attn_out[orow1] = acc1;
}

// ---------------------------------------------------------------------------
// Kernel 3: projection GEMM + bias. M=16384, K=768, N=768.
// ---------------------------------------------------------------------------
__global__ __launch_bounds__(256) void proj_gemm_kernel(
    const float* __restrict__ A, const float* __restrict__ W,
    const float* __restrict__ bias, float* __restrict__ out)
{
    __shared__ float As[16][68];
    __shared__ float Bs[16][64];

    const int t  = threadIdx.x;
    const int n0 = blockIdx.x * 64;
    const int m0 = blockIdx.y * 64;

    const int ar = t >> 2;
    const int ac = (t & 3) * 4;
    const float* arow = A + (size_t)(m0 + ar) * CC;

    const int br = t >> 4;
    const int bc = (t & 15) * 4;
    const float* bptr = W + (size_t)br * CC + n0 + bc;

    const int tm = (t & 15) * 4;
    const int tn = (t >> 4) * 4;

    float acc[4][4] = {};

    for (int k0 = 0; k0 < CC; k0 += 16) {
        float4 av = *(const float4*)(arow + k0 + ac);
        float4 bv = *(const float4*)(bptr + (size_t)k0 * CC);
        __syncthreads();
        As[ac + 0][ar] = av.x;
        As[ac + 1][ar] = av.y;
        As[ac + 2][ar] = av.z;
        As[ac + 3][ar] = av.w;
        *(float4*)(&Bs[br][bc]) = bv;
        __syncthreads();
#pragma unroll
        for (int kk = 0; kk < 16; ++kk) {
            float4 a4 = *(const float4*)(&As[kk][tm]);
            float4 b4 = *(const float4*)(&Bs[kk][tn]);
            float a[4] = {a4.x, a4.y, a4.z, a4.w};
            float b[4] = {b4.x, b4.y, b4.z, b4.w};
#pragma unroll
            for (int u = 0; u < 4; ++u)
#pragma unroll
                for (int v = 0; v < 4; ++v)
                    acc[u][v] = fmaf(a[u], b[v], acc[u][v]);
        }
    }

    const size_t obase = (size_t)(m0 + tm) * CC + n0 + tn;
#pragma unroll
    for (int u = 0; u < 4; ++u)
#pragma unroll
        for (int v = 0; v < 4; ++v)
            out[obase + (size_t)u * CC + v] = acc[u][v] + bias[n0 + tn + v];
}

// ---------------------------------------------------------------------------
extern "C" void kernel_launch(void* const* d_in, const int* in_sizes, int n_in,
                              void* d_out, int out_size, void* d_ws, size_t ws_size,
                              hipStream_t stream) {
    const float* x      = (const float*)d_in[0];
    const float* sct    = (const float*)d_in[1];
    const float* W_qkv  = (const float*)d_in[2];
    const float* W_proj = (const float*)d_in[3];
    const float* b_proj = (const float*)d_in[4];
    float* out = (float*)d_out;

    // ws layout: qkv bf16 (19520 x 2304) = 89,948,160 B, then attn_out fp32
    // (16384 x 768) = 50,331,648 B. Total ~140 MB.
    __hip_bfloat16* qkv = (__hip_bfloat16*)d_ws;
    float* attn_out = (float*)((char*)d_ws + (size_t)M_QKV * N_QKV * sizeof(__hip_bfloat16));

    qkv_gemm_kernel<<<dim3(N_QKV / 64, M_QKV / 64), 256, 0, stream>>>(
        x, sct, W_qkv, qkv);
    attn_kernel<<<dim3(BB * HH * (NN / 8)), 256, 0, stream>>>(qkv, attn_out);
    proj_gemm_kernel<<<dim3(CC / 64, M_PROJ / 64), 256, 0, stream>>>(
        attn_out, W_proj, b_proj, out);
}

// Round 2
// 1409.286 us; speedup vs baseline: 4.4818x; 4.4818x over previous
//
#include <hip/hip_runtime.h>
#include <hip/hip_bf16.h>

// Problem constants
#define BB 16
#define NN 1024
#define CC 768
#define HH 12
#define DH 64
#define NSC 196
#define N1 1220              // NN + NSC
#define M_QKV (BB * N1)      // 19520
#define N_QKV (3 * CC)       // 2304
#define M_PROJ (BB * NN)     // 16384

typedef __attribute__((ext_vector_type(8))) short short8;   // 8 bf16 = 4 VGPRs
typedef __attribute__((ext_vector_type(4))) float f32x4;

// ---------------------------------------------------------------------------
// Kernel 1: QKV GEMM (fp32 vector, unchanged from R1).
// ---------------------------------------------------------------------------
__global__ __launch_bounds__(256) void qkv_gemm_kernel(
    const float* __restrict__ x, const float* __restrict__ sct,
    const float* __restrict__ W, __hip_bfloat16* __restrict__ out)
{
    __shared__ float As[16][68];
    __shared__ float Bs[16][64];

    const int t  = threadIdx.x;
    const int n0 = blockIdx.x * 64;
    const int m0 = blockIdx.y * 64;

    const int ar = t >> 2;
    const int ac = (t & 3) * 4;
    const int r  = m0 + ar;
    const int bidx = r / N1;
    const int rr   = r - bidx * N1;
    const float* arow = (rr < NN)
        ? (x   + ((size_t)bidx * NN + rr) * CC)
        : (sct + (size_t)(rr - NN) * CC);

    const int br = t >> 4;
    const int bc = (t & 15) * 4;
    const float* bptr = W + (size_t)br * N_QKV + n0 + bc;

    const int tm = (t & 15) * 4;
    const int tn = (t >> 4) * 4;

    float acc[4][4] = {};

    for (int k0 = 0; k0 < CC; k0 += 16) {
        float4 av = *(const float4*)(arow + k0 + ac);
        float4 bv = *(const float4*)(bptr + (size_t)k0 * N_QKV);
        __syncthreads();
        As[ac + 0][ar] = av.x;
        As[ac + 1][ar] = av.y;
        As[ac + 2][ar] = av.z;
        As[ac + 3][ar] = av.w;
        *(float4*)(&Bs[br][bc]) = bv;
        __syncthreads();
#pragma unroll
        for (int kk = 0; kk < 16; ++kk) {
            float4 a4 = *(const float4*)(&As[kk][tm]);
            float4 b4 = *(const float4*)(&Bs[kk][tn]);
            float a[4] = {a4.x, a4.y, a4.z, a4.w};
            float b[4] = {b4.x, b4.y, b4.z, b4.w};
#pragma unroll
            for (int u = 0; u < 4; ++u)
#pragma unroll
                for (int v = 0; v < 4; ++v)
                    acc[u][v] = fmaf(a[u], b[v], acc[u][v]);
        }
    }

    const size_t obase = (size_t)(m0 + tm) * N_QKV + n0 + tn;
#pragma unroll
    for (int u = 0; u < 4; ++u)
#pragma unroll
        for (int v = 0; v < 4; ++v)
            out[obase + (size_t)u * N_QKV + v] = __float2bfloat16(acc[u][v]);
}

// ---------------------------------------------------------------------------
// Kernel 2: flash-style MFMA attention.
// Block = (qt, h, b): 64 queries, 4 waves x 16 q each. Key tiles of 64.
// Computes S^T = K.Q^T (M=keys, N=q) so softmax stats are scalar per lane
// (q = lane&15). P round-trips through LDS into A-layout; V is staged
// transposed in LDS for the PV B-operand. Q/K fragments read directly
// from global (contiguous 16B per lane).
// ---------------------------------------------------------------------------
__global__ __launch_bounds__(256, 4) void attn_mfma_kernel(
    const __hip_bfloat16* __restrict__ qkv, float* __restrict__ attn_out)
{
    __shared__ short VT[64 * 72];        // V^T tile [d][key], 9216 B (pad 8)
    __shared__ short Pl[4 * 16 * 72];    // per-wave P [q][key], 9216 B

    const int t    = threadIdx.x;
    const int l15  = t & 15;
    const int quad = (t >> 4) & 3;
    const int w    = t >> 6;

    const int qt = blockIdx.x;
    const int h  = blockIdx.y;
    const int b  = blockIdx.z;

    const size_t rowbase = (size_t)b * N1;
    const __hip_bfloat16* qb = qkv + rowbase * N_QKV + h * DH;            // Q cols
    const __hip_bfloat16* kb = qkv + rowbase * N_QKV + CC + h * DH;       // K cols
    const __hip_bfloat16* vb = qkv + rowbase * N_QKV + 2 * CC + h * DH;   // V cols

    // Q fragments (B-operand of S^T): lane holds Q[q=l15][d=quad*8+j]
    short8 qf[2];
    {
        const size_t qrow = (size_t)(qt * 64 + w * 16 + l15);
#pragma unroll
        for (int ks = 0; ks < 2; ++ks)
            qf[ks] = *(const short8*)(qb + qrow * N_QKV + ks * 32 + quad * 8);
    }

    f32x4 oac[4];
#pragma unroll
    for (int dt = 0; dt < 4; ++dt) {
        oac[dt][0] = 0.f; oac[dt][1] = 0.f; oac[dt][2] = 0.f; oac[dt][3] = 0.f;
    }
    float mrun = -1e30f, lrun = 0.f;

    short* Pw = Pl + (w * 16) * 72;

    for (int k0 = 0; k0 < N1; k0 += 64) {
        // ---- V chunks (2x16B per thread) + K fragments from global ----
        short8 vchunk[2];
        int vkey[2], vd0[2];
#pragma unroll
        for (int c = 0; c < 2; ++c) {
            const int chunk = t * 2 + c;       // 0..511
            vkey[c] = chunk >> 3;              // key within tile
            vd0[c]  = (chunk & 7) * 8;         // d base
            if (k0 + vkey[c] < N1) {
                vchunk[c] = *(const short8*)(vb + (size_t)(k0 + vkey[c]) * N_QKV + vd0[c]);
            } else {
#pragma unroll
                for (int j = 0; j < 8; ++j) vchunk[c][j] = 0;
            }
        }
        short8 kf[4][2];   // A-operand: lane holds K[key=mt*16+l15][d=quad*8+j]
#pragma unroll
        for (int mt = 0; mt < 4; ++mt) {
            int krow = k0 + mt * 16 + l15;
            krow = krow < N1 ? krow : (N1 - 1);
#pragma unroll
            for (int ks = 0; ks < 2; ++ks)
                kf[mt][ks] = *(const short8*)(kb + (size_t)krow * N_QKV + ks * 32 + quad * 8);
        }

        __syncthreads();                       // prior tile's VT reads done
#pragma unroll
        for (int c = 0; c < 2; ++c)
#pragma unroll
            for (int j = 0; j < 8; ++j)
                VT[(vd0[c] + j) * 72 + vkey[c]] = vchunk[c][j];
        __syncthreads();                       // VT staged

        // ---- S^T = K . Q^T : C[row=key(quad*4+r), col=q(l15)] ----
        f32x4 st[4];
#pragma unroll
        for (int mt = 0; mt < 4; ++mt) {
            st[mt][0] = 0.f; st[mt][1] = 0.f; st[mt][2] = 0.f; st[mt][3] = 0.f;
        }
#pragma unroll
        for (int ks = 0; ks < 2; ++ks)
#pragma unroll
            for (int mt = 0; mt < 4; ++mt)
                st[mt] = __builtin_amdgcn_mfma_f32_16x16x32_bf16(kf[mt][ks], qf[ks], st[mt], 0, 0, 0);

        // ---- online softmax: column stats for q = l15 ----
        const bool edge = (k0 + 64 > N1);
        float smax = -1e30f;
#pragma unroll
        for (int mt = 0; mt < 4; ++mt)
#pragma unroll
            for (int r = 0; r < 4; ++r) {
                float v = st[mt][r] * 0.125f;  // scale = Dh^-0.5 = 1/8
                if (edge && (k0 + mt * 16 + quad * 4 + r >= N1)) v = -1e30f;
                st[mt][r] = v;
                smax = fmaxf(smax, v);
            }
        smax = fmaxf(smax, __shfl_xor(smax, 16));
        smax = fmaxf(smax, __shfl_xor(smax, 32));
        const float mnew  = fmaxf(mrun, smax);
        const float alpha = __expf(mrun - mnew);
        float rsum = 0.f;
#pragma unroll
        for (int mt = 0; mt < 4; ++mt)
#pragma unroll
            for (int r = 0; r < 4; ++r) {
                float p = __expf(st[mt][r] - mnew);
                st[mt][r] = p;
                rsum += p;
            }
        rsum += __shfl_xor(rsum, 16);
        rsum += __shfl_xor(rsum, 32);
        lrun = lrun * alpha + rsum;
        mrun = mnew;

        // rescale O (rows q = quad*4+r need alpha from lane quad*4+r)
#pragma unroll
        for (int r = 0; r < 4; ++r) {
            const float ar = __shfl(alpha, quad * 4 + r);
#pragma unroll
            for (int dt = 0; dt < 4; ++dt) oac[dt][r] *= ar;
        }

        // ---- P -> LDS as bf16 in [q][key] (A-layout for PV) ----
#pragma unroll
        for (int mt = 0; mt < 4; ++mt) {
            union { unsigned long long u; __hip_bfloat16 hh[4]; } pk;
#pragma unroll
            for (int r = 0; r < 4; ++r) pk.hh[r] = __float2bfloat16(st[mt][r]);
            *(unsigned long long*)&Pw[l15 * 72 + mt * 16 + quad * 4] = pk.u;
        }

        // ---- O += P . V ----
#pragma unroll
        for (int ks = 0; ks < 2; ++ks) {
            const short8 pf = *(const short8*)&Pw[l15 * 72 + ks * 32 + quad * 8];
#pragma unroll
            for (int dt = 0; dt < 4; ++dt) {
                const short8 vf = *(const short8*)&VT[(l15 + 16 * dt) * 72 + ks * 32 + quad * 8];
                oac[dt] = __builtin_amdgcn_mfma_f32_16x16x32_bf16(pf, vf, oac[dt], 0, 0, 0);
            }
        }
    }

    // ---- finalize: divide by l, write fp32 ----
    const float li = 1.0f / lrun;
#pragma unroll
    for (int r = 0; r < 4; ++r) {
        const float ir = __shfl(li, quad * 4 + r);
        const int qrow = qt * 64 + w * 16 + quad * 4 + r;
        float* orow = attn_out + ((size_t)b * NN + qrow) * CC + h * DH;
#pragma unroll
        for (int dt = 0; dt < 4; ++dt)
            orow[l15 + 16 * dt] = oac[dt][r] * ir;
    }
}

// ---------------------------------------------------------------------------
// Kernel 3: projection GEMM + bias (fp32 vector, unchanged from R1).
// ---------------------------------------------------------------------------
__global__ __launch_bounds__(256) void proj_gemm_kernel(
    const float* __restrict__ A, const float* __restrict__ W,
    const float* __restrict__ bias, float* __restrict__ out)
{
    __shared__ float As[16][68];
    __shared__ float Bs[16][64];

    const int t  = threadIdx.x;
    const int n0 = blockIdx.x * 64;
    const int m0 = blockIdx.y * 64;

    const int ar = t >> 2;
    const int ac = (t & 3) * 4;
    const float* arow = A + (size_t)(m0 + ar) * CC;

    const int br = t >> 4;
    const int bc = (t & 15) * 4;
    const float* bptr = W + (size_t)br * CC + n0 + bc;

    const int tm = (t & 15) * 4;
    const int tn = (t >> 4) * 4;

    float acc[4][4] = {};

    for (int k0 = 0; k0 < CC; k0 += 16) {
        float4 av = *(const float4*)(arow + k0 + ac);
        float4 bv = *(const float4*)(bptr + (size_t)k0 * CC);
        __syncthreads();
        As[ac + 0][ar] = av.x;
        As[ac + 1][ar] = av.y;
        As[ac + 2][ar] = av.z;
        As[ac + 3][ar] = av.w;
        *(float4*)(&Bs[br][bc]) = bv;
        __syncthreads();
#pragma unroll
        for (int kk = 0; kk < 16; ++kk) {
            float4 a4 = *(const float4*)(&As[kk][tm]);
            float4 b4 = *(const float4*)(&Bs[kk][tn]);
            float a[4] = {a4.x, a4.y, a4.z, a4.w};
            float b[4] = {b4.x, b4.y, b4.z, b4.w};
#pragma unroll
            for (int u = 0; u < 4; ++u)
#pragma unroll
                for (int v = 0; v < 4; ++v)
                    acc[u][v] = fmaf(a[u], b[v], acc[u][v]);
        }
    }

    const size_t obase = (size_t)(m0 + tm) * CC + n0 + tn;
#pragma unroll
    for (int u = 0; u < 4; ++u)
#pragma unroll
        for (int v = 0; v < 4; ++v)
            out[obase + (size_t)u * CC + v] = acc[u][v] + bias[n0 + tn + v];
}

// ---------------------------------------------------------------------------
extern "C" void kernel_launch(void* const* d_in, const int* in_sizes, int n_in,
                              void* d_out, int out_size, void* d_ws, size_t ws_size,
                              hipStream_t stream) {
    const float* x      = (const float*)d_in[0];
    const float* sct    = (const float*)d_in[1];
    const float* W_qkv  = (const float*)d_in[2];
    const float* W_proj = (const float*)d_in[3];
    const float* b_proj = (const float*)d_in[4];
    float* out = (float*)d_out;

    __hip_bfloat16* qkv = (__hip_bfloat16*)d_ws;
    float* attn_out = (float*)((char*)d_ws + (size_t)M_QKV * N_QKV * sizeof(__hip_bfloat16));

    qkv_gemm_kernel<<<dim3(N_QKV / 64, M_QKV / 64), 256, 0, stream>>>(
        x, sct, W_qkv, qkv);
    attn_mfma_kernel<<<dim3(NN / 64, HH, BB), 256, 0, stream>>>(qkv, attn_out);
    proj_gemm_kernel<<<dim3(CC / 64, M_PROJ / 64), 256, 0, stream>>>(
        attn_out, W_proj, b_proj, out);
}

// Round 3
// 499.388 us; speedup vs baseline: 12.6477x; 2.8220x over previous
//
#include <hip/hip_runtime.h>
#include <hip/hip_bf16.h>

// Problem constants
#define BB 16
#define NN 1024
#define CC 768
#define HH 12
#define DH 64
#define NSC 196
#define N1 1220              // NN + NSC
#define MPAD 19584           // 153*128, padded row count of xt
#define M_QKV (BB * N1)      // 19520 (valid rows)
#define N_QKV (3 * CC)       // 2304
#define M_PROJ (BB * NN)     // 16384

typedef __attribute__((ext_vector_type(8))) short short8;   // 8 bf16 = 4 VGPRs
typedef __attribute__((ext_vector_type(4))) float f32x4;

__device__ __forceinline__ void load_lds16(const void* g, void* l) {
    __builtin_amdgcn_global_load_lds(
        (__attribute__((address_space(1))) void*)(g),
        (__attribute__((address_space(3))) void*)(l),
        16, 0, 0);
}

// ---------------------------------------------------------------------------
// Cast kernels (one-time, ~µs): build bf16 xt (concat + zero-pad) and
// transposed bf16 weights so the GEMM's B operand is row-major [n][k].
// ---------------------------------------------------------------------------
__global__ __launch_bounds__(256) void cast_xt_kernel(
    const float* __restrict__ x, const float* __restrict__ sct,
    __hip_bfloat16* __restrict__ xt)
{
    const int e   = blockIdx.x * 256 + threadIdx.x;   // MPAD*96 threads
    const int row = e / 96;
    const int c8  = (e - row * 96) * 8;
    union { short8 s; __hip_bfloat16 h[8]; } u;
    if (row < M_QKV) {
        const int b  = row / N1;
        const int rr = row - b * N1;
        const float* src = (rr < NN)
            ? x   + ((size_t)b * NN + rr) * CC + c8
            : sct + (size_t)(rr - NN) * CC + c8;
        const float4 v0 = *(const float4*)src;
        const float4 v1 = *(const float4*)(src + 4);
        u.h[0] = __float2bfloat16(v0.x); u.h[1] = __float2bfloat16(v0.y);
        u.h[2] = __float2bfloat16(v0.z); u.h[3] = __float2bfloat16(v0.w);
        u.h[4] = __float2bfloat16(v1.x); u.h[5] = __float2bfloat16(v1.y);
        u.h[6] = __float2bfloat16(v1.z); u.h[7] = __float2bfloat16(v1.w);
    } else {
#pragma unroll
        for (int j = 0; j < 8; ++j) u.h[j] = __float2bfloat16(0.f);
    }
    *(short8*)(xt + (size_t)row * CC + c8) = u.s;
}

// W: [K=768][Ncols] fp32 -> WT: [Ncols][768] bf16 (coalesced writes)
__global__ __launch_bounds__(256) void cast_wt_kernel(
    const float* __restrict__ W, __hip_bfloat16* __restrict__ WT, int Ncols)
{
    const int e  = blockIdx.x * 256 + threadIdx.x;    // Ncols*96 threads
    const int n  = e / 96;
    const int k8 = (e - n * 96) * 8;
    union { short8 s; __hip_bfloat16 h[8]; } u;
#pragma unroll
    for (int j = 0; j < 8; ++j)
        u.h[j] = __float2bfloat16(W[(size_t)(k8 + j) * Ncols + n]);
    *(short8*)(WT + (size_t)n * CC + k8) = u.s;
}

// ---------------------------------------------------------------------------
// m97-style MFMA GEMM: C = A . BT^T.  A [M][K] bf16 row-major, BT [N][K]
// bf16 row-major. 128x128 tile, BK=32, 256 threads (4 waves, 64x64 each),
// global_load_lds width-16 staging, 2-barrier K-loop.
// ---------------------------------------------------------------------------
template <bool WRITE_BF16>
__global__ __launch_bounds__(256) void mfma_gemm_bt(
    const __hip_bfloat16* __restrict__ A,
    const __hip_bfloat16* __restrict__ BT,
    void* __restrict__ Cout,
    const float* __restrict__ bias,
    int K, int ldc)
{
    __shared__ __hip_bfloat16 As[128 * 32];
    __shared__ __hip_bfloat16 Bs[128 * 32];

    const int t    = threadIdx.x;
    const int lane = t & 63;
    const int l15  = lane & 15;
    const int quad = lane >> 4;
    const int w    = t >> 6;
    const int wm   = w & 1;
    const int wn   = w >> 1;

    const int n0 = blockIdx.x * 128;
    const int m0 = blockIdx.y * 128;

    // staging: thread t covers byte offsets f0 and f0+4096 of each 8 KB tile
    const int f0 = t * 16;               // bytes; row = f>>6, colbyte = f&63
    const int r0 = f0 >> 6, c0 = (f0 & 63) >> 1;
    const int r1 = (f0 + 4096) >> 6, c1 = c0;

    const __hip_bfloat16* gA0 = A  + (size_t)(m0 + r0) * K + c0;
    const __hip_bfloat16* gA1 = A  + (size_t)(m0 + r1) * K + c1;
    const __hip_bfloat16* gB0 = BT + (size_t)(n0 + r0) * K + c0;
    const __hip_bfloat16* gB1 = BT + (size_t)(n0 + r1) * K + c1;

    __hip_bfloat16* lA0 = As + r0 * 32 + c0;
    __hip_bfloat16* lA1 = As + r1 * 32 + c1;
    __hip_bfloat16* lB0 = Bs + r0 * 32 + c0;
    __hip_bfloat16* lB1 = Bs + r1 * 32 + c1;

    f32x4 acc[4][4];
#pragma unroll
    for (int mi = 0; mi < 4; ++mi)
#pragma unroll
        for (int ni = 0; ni < 4; ++ni) {
            acc[mi][ni][0] = 0.f; acc[mi][ni][1] = 0.f;
            acc[mi][ni][2] = 0.f; acc[mi][ni][3] = 0.f;
        }

    for (int k0 = 0; k0 < K; k0 += 32) {
        __syncthreads();                 // previous tile's readers done
        load_lds16(gA0, lA0);
        load_lds16(gA1, lA1);
        load_lds16(gB0, lB0);
        load_lds16(gB1, lB1);
        gA0 += 32; gA1 += 32; gB0 += 32; gB1 += 32;
        __syncthreads();                 // staging drained (vmcnt(0) at barrier)

        short8 af[4], bf_[4];
#pragma unroll
        for (int mi = 0; mi < 4; ++mi)
            af[mi] = *(const short8*)&As[(wm * 64 + mi * 16 + l15) * 32 + quad * 8];
#pragma unroll
        for (int ni = 0; ni < 4; ++ni)
            bf_[ni] = *(const short8*)&Bs[(wn * 64 + ni * 16 + l15) * 32 + quad * 8];
#pragma unroll
        for (int mi = 0; mi < 4; ++mi)
#pragma unroll
            for (int ni = 0; ni < 4; ++ni)
                acc[mi][ni] = __builtin_amdgcn_mfma_f32_16x16x32_bf16(
                    af[mi], bf_[ni], acc[mi][ni], 0, 0, 0);
    }

    // epilogue: C/D layout col = l15, row = quad*4 + reg
#pragma unroll
    for (int mi = 0; mi < 4; ++mi) {
        const int rowb = m0 + wm * 64 + mi * 16 + quad * 4;
#pragma unroll
        for (int ni = 0; ni < 4; ++ni) {
            const int col = n0 + wn * 64 + ni * 16 + l15;
#pragma unroll
            for (int r = 0; r < 4; ++r) {
                const size_t idx = (size_t)(rowb + r) * ldc + col;
                if (WRITE_BF16)
                    ((__hip_bfloat16*)Cout)[idx] = __float2bfloat16(acc[mi][ni][r]);
                else
                    ((float*)Cout)[idx] = acc[mi][ni][r] + bias[col];
            }
        }
    }
}

// ---------------------------------------------------------------------------
// Flash-style MFMA attention (R2, unchanged except bf16 output).
// ---------------------------------------------------------------------------
__global__ __launch_bounds__(256, 4) void attn_mfma_kernel(
    const __hip_bfloat16* __restrict__ qkv, __hip_bfloat16* __restrict__ attn_out)
{
    __shared__ short VT[64 * 72];
    __shared__ short Pl[4 * 16 * 72];

    const int t    = threadIdx.x;
    const int l15  = t & 15;
    const int quad = (t >> 4) & 3;
    const int w    = t >> 6;

    const int qt = blockIdx.x;
    const int h  = blockIdx.y;
    const int b  = blockIdx.z;

    const size_t rowbase = (size_t)b * N1;
    const __hip_bfloat16* qb = qkv + rowbase * N_QKV + h * DH;
    const __hip_bfloat16* kb = qkv + rowbase * N_QKV + CC + h * DH;
    const __hip_bfloat16* vb = qkv + rowbase * N_QKV + 2 * CC + h * DH;

    short8 qf[2];
    {
        const size_t qrow = (size_t)(qt * 64 + w * 16 + l15);
#pragma unroll
        for (int ks = 0; ks < 2; ++ks)
            qf[ks] = *(const short8*)(qb + qrow * N_QKV + ks * 32 + quad * 8);
    }

    f32x4 oac[4];
#pragma unroll
    for (int dt = 0; dt < 4; ++dt) {
        oac[dt][0] = 0.f; oac[dt][1] = 0.f; oac[dt][2] = 0.f; oac[dt][3] = 0.f;
    }
    float mrun = -1e30f, lrun = 0.f;

    short* Pw = Pl + (w * 16) * 72;

    for (int k0 = 0; k0 < N1; k0 += 64) {
        short8 vchunk[2];
        int vkey[2], vd0[2];
#pragma unroll
        for (int c = 0; c < 2; ++c) {
            const int chunk = t * 2 + c;
            vkey[c] = chunk >> 3;
            vd0[c]  = (chunk & 7) * 8;
            if (k0 + vkey[c] < N1) {
                vchunk[c] = *(const short8*)(vb + (size_t)(k0 + vkey[c]) * N_QKV + vd0[c]);
            } else {
#pragma unroll
                for (int j = 0; j < 8; ++j) vchunk[c][j] = 0;
            }
        }
        short8 kf[4][2];
#pragma unroll
        for (int mt = 0; mt < 4; ++mt) {
            int krow = k0 + mt * 16 + l15;
            krow = krow < N1 ? krow : (N1 - 1);
#pragma unroll
            for (int ks = 0; ks < 2; ++ks)
                kf[mt][ks] = *(const short8*)(kb + (size_t)krow * N_QKV + ks * 32 + quad * 8);
        }

        __syncthreads();
#pragma unroll
        for (int c = 0; c < 2; ++c)
#pragma unroll
            for (int j = 0; j < 8; ++j)
                VT[(vd0[c] + j) * 72 + vkey[c]] = vchunk[c][j];
        __syncthreads();

        f32x4 st[4];
#pragma unroll
        for (int mt = 0; mt < 4; ++mt) {
            st[mt][0] = 0.f; st[mt][1] = 0.f; st[mt][2] = 0.f; st[mt][3] = 0.f;
        }
#pragma unroll
        for (int ks = 0; ks < 2; ++ks)
#pragma unroll
            for (int mt = 0; mt < 4; ++mt)
                st[mt] = __builtin_amdgcn_mfma_f32_16x16x32_bf16(kf[mt][ks], qf[ks], st[mt], 0, 0, 0);

        const bool edge = (k0 + 64 > N1);
        float smax = -1e30f;
#pragma unroll
        for (int mt = 0; mt < 4; ++mt)
#pragma unroll
            for (int r = 0; r < 4; ++r) {
                float v = st[mt][r] * 0.125f;
                if (edge && (k0 + mt * 16 + quad * 4 + r >= N1)) v = -1e30f;
                st[mt][r] = v;
                smax = fmaxf(smax, v);
            }
        smax = fmaxf(smax, __shfl_xor(smax, 16));
        smax = fmaxf(smax, __shfl_xor(smax, 32));
        const float mnew  = fmaxf(mrun, smax);
        const float alpha = __expf(mrun - mnew);
        float rsum = 0.f;
#pragma unroll
        for (int mt = 0; mt < 4; ++mt)
#pragma unroll
            for (int r = 0; r < 4; ++r) {
                float p = __expf(st[mt][r] - mnew);
                st[mt][r] = p;
                rsum += p;
            }
        rsum += __shfl_xor(rsum, 16);
        rsum += __shfl_xor(rsum, 32);
        lrun = lrun * alpha + rsum;
        mrun = mnew;

#pragma unroll
        for (int r = 0; r < 4; ++r) {
            const float ar = __shfl(alpha, quad * 4 + r);
#pragma unroll
            for (int dt = 0; dt < 4; ++dt) oac[dt][r] *= ar;
        }

#pragma unroll
        for (int mt = 0; mt < 4; ++mt) {
            union { unsigned long long u; __hip_bfloat16 hh[4]; } pk;
#pragma unroll
            for (int r = 0; r < 4; ++r) pk.hh[r] = __float2bfloat16(st[mt][r]);
            *(unsigned long long*)&Pw[l15 * 72 + mt * 16 + quad * 4] = pk.u;
        }

#pragma unroll
        for (int ks = 0; ks < 2; ++ks) {
            const short8 pf = *(const short8*)&Pw[l15 * 72 + ks * 32 + quad * 8];
#pragma unroll
            for (int dt = 0; dt < 4; ++dt) {
                const short8 vf = *(const short8*)&VT[(l15 + 16 * dt) * 72 + ks * 32 + quad * 8];
                oac[dt] = __builtin_amdgcn_mfma_f32_16x16x32_bf16(pf, vf, oac[dt], 0, 0, 0);
            }
        }
    }

    const float li = 1.0f / lrun;
#pragma unroll
    for (int r = 0; r < 4; ++r) {
        const float ir = __shfl(li, quad * 4 + r);
        const int qrow = qt * 64 + w * 16 + quad * 4 + r;
        __hip_bfloat16* orow = attn_out + ((size_t)b * NN + qrow) * CC + h * DH;
#pragma unroll
        for (int dt = 0; dt < 4; ++dt)
            orow[l15 + 16 * dt] = __float2bfloat16(oac[dt][r] * ir);
    }
}

// ---------------------------------------------------------------------------
extern "C" void kernel_launch(void* const* d_in, const int* in_sizes, int n_in,
                              void* d_out, int out_size, void* d_ws, size_t ws_size,
                              hipStream_t stream) {
    const float* x      = (const float*)d_in[0];
    const float* sct    = (const float*)d_in[1];
    const float* W_qkv  = (const float*)d_in[2];
    const float* W_proj = (const float*)d_in[3];
    const float* b_proj = (const float*)d_in[4];
    float* out = (float*)d_out;

    // ws layout (bytes):
    //   xt      bf16 [19584][768]  = 30,081,024   (attn_out bf16 aliases this)
    //   qkv     bf16 [19584][2304] = 90,243,072
    //   WT_qkv  bf16 [2304][768]   =  3,538,944
    //   WT_proj bf16 [768][768]    =  1,179,648   -> total 125.0 MB
    char* p = (char*)d_ws;
    __hip_bfloat16* xt      = (__hip_bfloat16*)p;
    __hip_bfloat16* attn_o  = (__hip_bfloat16*)p;            // aliases xt
    __hip_bfloat16* qkv     = (__hip_bfloat16*)(p + (size_t)MPAD * CC * 2);
    __hip_bfloat16* WTqkv   = (__hip_bfloat16*)(p + (size_t)MPAD * CC * 2 + (size_t)MPAD * N_QKV * 2);
    __hip_bfloat16* WTproj  = WTqkv + (size_t)N_QKV * CC;

    cast_xt_kernel<<<MPAD * 96 / 256, 256, 0, stream>>>(x, sct, xt);
    cast_wt_kernel<<<N_QKV * 96 / 256, 256, 0, stream>>>(W_qkv, WTqkv, N_QKV);
    cast_wt_kernel<<<CC * 96 / 256, 256, 0, stream>>>(W_proj, WTproj, CC);

    mfma_gemm_bt<true><<<dim3(N_QKV / 128, MPAD / 128), 256, 0, stream>>>(
        xt, WTqkv, qkv, nullptr, CC, N_QKV);
    attn_mfma_kernel<<<dim3(NN / 64, HH, BB), 256, 0, stream>>>(qkv, attn_o);
    mfma_gemm_bt<false><<<dim3(CC / 128, M_PROJ / 128), 256, 0, stream>>>(
        attn_o, WTproj, out, b_proj, CC, CC);
}